// Round 4
// baseline (125.030 us; speedup 1.0000x reference)
//
#include <hip/hip_runtime.h>

// NT-Xent (SimCLR) loss, B=2048, D=256, N=4096, T=0.5, eps=1e-8.
// R4: launch-count is the controllable bottleneck (42us of the 80 is the
// harness's fixed 256MB d_ws poison fill; our 4 kernels cost more in
// gaps/overhead than in work). Collapse to 2 kernels:
//  k1: triangle-tiled sim GEMM on UNNORMALIZED bf16 z; row norms from fp32
//      square-sums accumulated during staging (free); normalize in epilogue
//      as acc * invn_r * invn_c * 2.  Emits row+col exp-sums + positives.
//  k2: single-block (1024 thr) finalize: log(sum)-pos, mean.

#define NROWS 4096
#define DDIM 256
#define BHALF 2048
#define TILE 128
#define BK 64
#define LDP 72      // padded LDS row stride (shorts): 144B = 9*16B, 2-way banks (free)
#define NCB 32      // 4096/128 tile indices
#define INV_T 2.0f

typedef short bf16x8 __attribute__((ext_vector_type(8)));
typedef float f32x4 __attribute__((ext_vector_type(4)));

// pack two fp32 -> bf16x2 (round-half-away via +0x8000, then byte-perm)
__device__ inline unsigned bfpack(float lo, float hi) {
    union { float f; unsigned u; } a, b;
    a.f = lo; b.f = hi;
    // sel 0x07060302: dst = {hi.b3,hi.b2, lo.b3,lo.b2}; src1 bytes are 0-3
    return __builtin_amdgcn_perm(b.u + 0x8000u, a.u + 0x8000u, 0x07060302u);
}

// ---- Kernel 1: fused normalize + upper-triangle sim GEMM + exp-sums -------
// grid = 528 blocks -> (bx,by), by>=bx; 256 thr = 2x2 waves, wave = 64x64 out.
__global__ __launch_bounds__(256) void k_simlse(
    const float* __restrict__ zi, const float* __restrict__ zj,
    float* __restrict__ partial,     // [NCB][4096], each slot exactly 1 writer
    float* __restrict__ posv) {      // [4096]
    __shared__ unsigned short As[TILE * LDP];
    __shared__ unsigned short Bs[TILE * LDP];
    __shared__ float rnA[TILE], rnB[TILE];   // inverse norms
    __shared__ float pscratch[TILE], cscratch[TILE];

    // triangle decode: block t -> (bx, by), by >= bx
    int t = blockIdx.x, bx = 0, rem = NCB;
    while (t >= rem) { t -= rem; ++bx; --rem; }
    const int by = bx + t;

    const int tid = threadIdx.x;
    const int wave = tid >> 6, lane = tid & 63;
    const int quad = lane >> 4, l15 = lane & 15;
    const int wr = wave >> 1, wc = wave & 1;
    const int rowBase = bx * TILE;
    const int colBase = by * TILE;
    // each 128-row tile lives entirely in zi (bx<16) or zj (bx>=16)
    const float* srcA = (bx < 16) ? (zi + rowBase * DDIM)
                                  : (zj + (rowBase - BHALF) * DDIM);
    const float* srcB = (by < 16) ? (zi + colBase * DDIM)
                                  : (zj + (colBase - BHALF) * DDIM);

    const int c8 = tid & 7;          // this thread's 8-float chunk (constant)
    float sqA[4] = {}, sqB[4] = {};  // fp32 square-sums, rows (tid>>3)+i*32
    f32x4 acc[4][4] = {};

    #pragma unroll
    for (int kb = 0; kb < DDIM / BK; ++kb) {
        __syncthreads();   // previous compute done before LDS overwrite
        #pragma unroll
        for (int i = 0; i < 4; ++i) {
            const int r = (tid >> 3) + i * 32;
            const float* pa = srcA + r * DDIM + kb * BK + c8 * 8;
            const float* pb = srcB + r * DDIM + kb * BK + c8 * 8;
            const float4 a0 = *(const float4*)pa, a1 = *(const float4*)(pa + 4);
            const float4 b0 = *(const float4*)pb, b1 = *(const float4*)(pb + 4);
            sqA[i] += a0.x*a0.x + a0.y*a0.y + a0.z*a0.z + a0.w*a0.w
                    + a1.x*a1.x + a1.y*a1.y + a1.z*a1.z + a1.w*a1.w;
            sqB[i] += b0.x*b0.x + b0.y*b0.y + b0.z*b0.z + b0.w*b0.w
                    + b1.x*b1.x + b1.y*b1.y + b1.z*b1.z + b1.w*b1.w;
            uint4 pkA = { bfpack(a0.x,a0.y), bfpack(a0.z,a0.w),
                          bfpack(a1.x,a1.y), bfpack(a1.z,a1.w) };
            uint4 pkB = { bfpack(b0.x,b0.y), bfpack(b0.z,b0.w),
                          bfpack(b1.x,b1.y), bfpack(b1.z,b1.w) };
            *(uint4*)&As[r * LDP + c8 * 8] = pkA;
            *(uint4*)&Bs[r * LDP + c8 * 8] = pkB;
        }
        __syncthreads();
        #pragma unroll
        for (int s = 0; s < 2; ++s) {
            bf16x8 af[4], bf[4];
            #pragma unroll
            for (int mt = 0; mt < 4; ++mt)
                af[mt] = *(const bf16x8*)&As[(wr * 64 + mt * 16 + l15) * LDP + s * 32 + quad * 8];
            #pragma unroll
            for (int nt = 0; nt < 4; ++nt)
                bf[nt] = *(const bf16x8*)&Bs[(wc * 64 + nt * 16 + l15) * LDP + s * 32 + quad * 8];
            #pragma unroll
            for (int mt = 0; mt < 4; ++mt)
                #pragma unroll
                for (int nt = 0; nt < 4; ++nt)
                    acc[mt][nt] = __builtin_amdgcn_mfma_f32_16x16x32_bf16(
                        af[mt], bf[nt], acc[mt][nt], 0, 0, 0);
        }
    }

    // Inverse norms: reduce square-sums across the 8 staging lanes per row.
    #pragma unroll
    for (int i = 0; i < 4; ++i) {
        float a = sqA[i], b = sqB[i];
        a += __shfl_xor(a, 1); a += __shfl_xor(a, 2); a += __shfl_xor(a, 4);
        b += __shfl_xor(b, 1); b += __shfl_xor(b, 2); b += __shfl_xor(b, 4);
        if (c8 == 0) {
            const int r = (tid >> 3) + i * 32;
            rnA[r] = 1.0f / fmaxf(sqrtf(a), 1e-8f);
            rnB[r] = 1.0f / fmaxf(sqrtf(b), 1e-8f);
        }
    }
    __syncthreads();

    // Epilogue. C/D layout: col = lane&15, row = quad*4 + r.
    f32x4 rna[4];
    float rnb[4];
    #pragma unroll
    for (int mt = 0; mt < 4; ++mt)
        rna[mt] = *(const f32x4*)&rnA[wr * 64 + mt * 16 + quad * 4];
    #pragma unroll
    for (int nt = 0; nt < 4; ++nt)
        rnb[nt] = rnB[wc * 64 + nt * 16 + l15];

    float rsum[4][4];          // row-sums (post-butterfly, all lanes)
    float csum[4] = {};        // per-lane col partials
    #pragma unroll
    for (int mt = 0; mt < 4; ++mt) {
        #pragma unroll
        for (int r = 0; r < 4; ++r) {
            const int grow = rowBase + wr * 64 + mt * 16 + quad * 4 + r;
            float s = 0.f;
            #pragma unroll
            for (int nt = 0; nt < 4; ++nt) {
                const int gcol = colBase + wc * 64 + nt * 16 + l15;
                const float simv = acc[mt][nt][r] * rna[mt][r] * rnb[nt] * INV_T;
                const float e = (gcol != grow) ? __expf(simv) : 0.f;
                s += e;
                csum[nt] += e;
                if (gcol == grow + BHALF) {   // only in by==bx+16 blocks
                    posv[grow] = simv;        // symmetric -> both rows
                    posv[gcol] = simv;
                }
            }
            s += __shfl_xor(s, 1); s += __shfl_xor(s, 2);
            s += __shfl_xor(s, 4); s += __shfl_xor(s, 8);
            rsum[mt][r] = s;
        }
    }
    #pragma unroll
    for (int nt = 0; nt < 4; ++nt) {    // reduce over row bits of lane
        csum[nt] += __shfl_xor(csum[nt], 16);
        csum[nt] += __shfl_xor(csum[nt], 32);
    }

    __syncthreads();
    if (wc == 0 && l15 == 0) {
        #pragma unroll
        for (int mt = 0; mt < 4; ++mt)
            #pragma unroll
            for (int r = 0; r < 4; ++r)
                pscratch[wr * 64 + mt * 16 + quad * 4 + r] = rsum[mt][r];
    }
    if (wr == 0 && quad == 0) {
        #pragma unroll
        for (int nt = 0; nt < 4; ++nt)
            cscratch[wc * 64 + nt * 16 + l15] = csum[nt];
    }
    __syncthreads();
    if (wc == 1 && l15 == 0) {          // row-sums -> partial[by][rowBase..]
        #pragma unroll
        for (int mt = 0; mt < 4; ++mt)
            #pragma unroll
            for (int r = 0; r < 4; ++r) {
                const int lr = wr * 64 + mt * 16 + quad * 4 + r;
                partial[by * NROWS + rowBase + lr] = rsum[mt][r] + pscratch[lr];
            }
    }
    if (bx != by && wr == 1 && quad == 0) {  // col-sums -> partial[bx][colBase..]
        #pragma unroll
        for (int nt = 0; nt < 4; ++nt) {
            const int lc = wc * 64 + nt * 16 + l15;
            partial[bx * NROWS + colBase + lc] = csum[nt] + cscratch[lc];
        }
    }
}

// ---- Kernel 2: single-block finalize: mean(log(sum) - pos) ----------------
__global__ __launch_bounds__(1024) void k_finalize(
    const float* __restrict__ partial, const float* __restrict__ posv,
    float* __restrict__ out) {
    __shared__ float red[16];
    const int tid = threadIdx.x;
    float acc = 0.f;
    #pragma unroll
    for (int rr = 0; rr < 4; ++rr) {
        const int row = tid + rr * 1024;
        float s = 0.f;
        #pragma unroll
        for (int p = 0; p < NCB; ++p) s += partial[p * NROWS + row];
        acc += __logf(s) - posv[row];
    }
    #pragma unroll
    for (int m = 1; m < 64; m <<= 1) acc += __shfl_xor(acc, m);
    if ((tid & 63) == 0) red[tid >> 6] = acc;
    __syncthreads();
    if (tid < 64) {
        float v = (tid < 16) ? red[tid] : 0.f;
        #pragma unroll
        for (int m = 1; m < 16; m <<= 1) v += __shfl_xor(v, m);
        if (tid == 0) out[0] = v * (1.0f / (float)NROWS);
    }
}

extern "C" void kernel_launch(void* const* d_in, const int* in_sizes, int n_in,
                              void* d_out, int out_size, void* d_ws, size_t ws_size,
                              hipStream_t stream) {
    const float* zi = (const float*)d_in[0];
    const float* zj = (const float*)d_in[1];
    float* out = (float*)d_out;

    float* partial = (float*)d_ws;           // 512 KB, every slot written
    float* posv = partial + NCB * NROWS;     // 16 KB, every slot written

    k_simlse<<<NCB * (NCB + 1) / 2, 256, 0, stream>>>(zi, zj, partial, posv);
    k_finalize<<<1, 1024, 0, stream>>>(partial, posv, out);
}

// Round 5
// 107.374 us; speedup vs baseline: 1.1644x; 1.1644x over previous
//
#include <hip/hip_runtime.h>

// NT-Xent (SimCLR) loss, B=2048, D=256, N=4096, T=0.5, eps=1e-8.
// R5: revert R4's fusion (fp32 staging + VGPR 172 -> 2 blocks/CU ->
// latency-bound, 42us). Back to R3's proven structure: bf16 zn staging
// (2MB, L2-resident) + triangle tiles; merge the two reduction kernels
// into one 1024-thread block (4 launches -> 3).
// Fixed harness floor: ~42us d_ws poison fill + d_in restore per iter.

#define NROWS 4096
#define DDIM 256
#define BHALF 2048
#define TILE 128
#define BK 64
#define LDP 72      // padded LDS row stride (shorts): 144B = 9*16B, 2-way banks (free)
#define NCB 32      // 4096/128 tile indices
#define INV_T 2.0f

typedef short bf16x8 __attribute__((ext_vector_type(8)));
typedef float f32x4 __attribute__((ext_vector_type(4)));

__device__ inline unsigned short f2bf(float f) {
    union { float f; unsigned u; } c; c.f = f;
    unsigned u = c.u + 0x7fffu + ((c.u >> 16) & 1u);  // RNE
    return (unsigned short)(u >> 16);
}

// ---- Kernel 1: row-normalize z=[z_i;z_j] into bf16 zn[4096][256] ----------
__global__ __launch_bounds__(256) void k_normalize(
    const float* __restrict__ zi, const float* __restrict__ zj,
    unsigned short* __restrict__ zn) {
    const int wave = threadIdx.x >> 6, lane = threadIdx.x & 63;
    const int row = blockIdx.x * 4 + wave;
    const float* src = (row < BHALF) ? (zi + row * DDIM)
                                     : (zj + (row - BHALF) * DDIM);
    const float4 v = ((const float4*)src)[lane];
    float ss = v.x * v.x + v.y * v.y + v.z * v.z + v.w * v.w;
    #pragma unroll
    for (int m = 1; m < 64; m <<= 1) ss += __shfl_xor(ss, m);
    const float scale = 1.0f / fmaxf(sqrtf(ss), 1e-8f);
    ushort4 o;
    o.x = f2bf(v.x * scale); o.y = f2bf(v.y * scale);
    o.z = f2bf(v.z * scale); o.w = f2bf(v.w * scale);
    ((ushort4*)(zn + row * DDIM))[lane] = o;
}

// ---- Kernel 2: upper-triangle LDS-tiled sim GEMM + exp-sum ----------------
// grid = 528 linear blocks -> (bx,by), by>=bx. Block 256 thr = 2x2 waves,
// each wave 64x64 via 4x4 mfma_f32_16x16x32_bf16.
__global__ __launch_bounds__(256) void k_simlse(
    const unsigned short* __restrict__ zn,
    float* __restrict__ partial,     // [NCB][4096], each slot 1 writer
    float* __restrict__ posv) {      // [4096]
    __shared__ unsigned short As[TILE * LDP];
    __shared__ unsigned short Bs[TILE * LDP];
    __shared__ float pscratch[TILE];   // row sums cross-wc
    __shared__ float cscratch[TILE];   // col sums cross-wr

    // triangle decode: block t -> (bx, by), by >= bx
    int t = blockIdx.x, bx = 0, rem = NCB;
    while (t >= rem) { t -= rem; ++bx; --rem; }
    const int by = bx + t;

    const int tid = threadIdx.x;
    const int wave = tid >> 6, lane = tid & 63;
    const int quad = lane >> 4, l15 = lane & 15;
    const int wr = wave >> 1, wc = wave & 1;
    const int rowBase = bx * TILE;
    const int colBase = by * TILE;

    f32x4 acc[4][4] = {};

    #pragma unroll
    for (int kb = 0; kb < DDIM / BK; ++kb) {
        __syncthreads();
        #pragma unroll
        for (int i = 0; i < 4; ++i) {
            const int flat = tid + i * 256;
            const int r = flat >> 3, c = flat & 7;
            *(bf16x8*)&As[r * LDP + c * 8] =
                *(const bf16x8*)&zn[(rowBase + r) * DDIM + kb * BK + c * 8];
            *(bf16x8*)&Bs[r * LDP + c * 8] =
                *(const bf16x8*)&zn[(colBase + r) * DDIM + kb * BK + c * 8];
        }
        __syncthreads();
        #pragma unroll
        for (int s = 0; s < 2; ++s) {
            bf16x8 af[4], bf[4];
            #pragma unroll
            for (int mt = 0; mt < 4; ++mt)
                af[mt] = *(const bf16x8*)&As[(wr * 64 + mt * 16 + l15) * LDP + s * 32 + quad * 8];
            #pragma unroll
            for (int nt = 0; nt < 4; ++nt)
                bf[nt] = *(const bf16x8*)&Bs[(wc * 64 + nt * 16 + l15) * LDP + s * 32 + quad * 8];
            #pragma unroll
            for (int mt = 0; mt < 4; ++mt)
                #pragma unroll
                for (int nt = 0; nt < 4; ++nt)
                    acc[mt][nt] = __builtin_amdgcn_mfma_f32_16x16x32_bf16(
                        af[mt], bf[nt], acc[mt][nt], 0, 0, 0);
        }
    }

    // Epilogue. C/D layout: col = lane&15, row = quad*4 + r.
    float rsum[4][4];          // [mt][r] row-sums (post-butterfly: all lanes)
    float csum[4] = {};        // [nt] per-lane col partial over 16 rows
    #pragma unroll
    for (int mt = 0; mt < 4; ++mt) {
        #pragma unroll
        for (int r = 0; r < 4; ++r) {
            const int grow = rowBase + wr * 64 + mt * 16 + quad * 4 + r;
            float s = 0.f;
            #pragma unroll
            for (int nt = 0; nt < 4; ++nt) {
                const int gcol = colBase + wc * 64 + nt * 16 + l15;
                const float simv = acc[mt][nt][r] * INV_T;
                const float e = (gcol != grow) ? __expf(simv) : 0.f;
                s += e;
                csum[nt] += e;
                if (gcol == grow + BHALF) {       // only in by==bx+16 blocks
                    posv[grow] = simv;            // sim symmetric -> both rows
                    posv[gcol] = simv;
                }
            }
            s += __shfl_xor(s, 1); s += __shfl_xor(s, 2);
            s += __shfl_xor(s, 4); s += __shfl_xor(s, 8);
            rsum[mt][r] = s;
        }
    }
    // col reduce across quads (row-index bits 4,5 of lane)
    #pragma unroll
    for (int nt = 0; nt < 4; ++nt) {
        csum[nt] += __shfl_xor(csum[nt], 16);
        csum[nt] += __shfl_xor(csum[nt], 32);
    }

    __syncthreads();
    if (wc == 0 && l15 == 0) {
        #pragma unroll
        for (int mt = 0; mt < 4; ++mt)
            #pragma unroll
            for (int r = 0; r < 4; ++r)
                pscratch[wr * 64 + mt * 16 + quad * 4 + r] = rsum[mt][r];
    }
    if (wr == 0 && quad == 0) {
        #pragma unroll
        for (int nt = 0; nt < 4; ++nt)
            cscratch[wc * 64 + nt * 16 + l15] = csum[nt];
    }
    __syncthreads();
    if (wc == 1 && l15 == 0) {    // row-sums -> partial[by][rowBase..]
        #pragma unroll
        for (int mt = 0; mt < 4; ++mt)
            #pragma unroll
            for (int r = 0; r < 4; ++r) {
                const int lr = wr * 64 + mt * 16 + quad * 4 + r;
                partial[by * NROWS + rowBase + lr] = rsum[mt][r] + pscratch[lr];
            }
    }
    if (bx != by && wr == 1 && quad == 0) {  // col-sums -> partial[bx][colBase..]
        #pragma unroll
        for (int nt = 0; nt < 4; ++nt) {
            const int lc = wc * 64 + nt * 16 + l15;
            partial[bx * NROWS + colBase + lc] = csum[nt] + cscratch[lc];
        }
    }
}

// ---- Kernel 3: single-block finalize: loss = mean(log(sum) - pos) ---------
__global__ __launch_bounds__(1024) void k_finalize(
    const float* __restrict__ partial, const float* __restrict__ posv,
    float* __restrict__ out) {
    __shared__ float red[16];
    const int tid = threadIdx.x;
    float acc = 0.f;
    #pragma unroll
    for (int rr = 0; rr < 4; ++rr) {
        const int row = tid + rr * 1024;
        float s = 0.f;
        #pragma unroll
        for (int p = 0; p < NCB; ++p) s += partial[p * NROWS + row];
        acc += __logf(s) - posv[row];
    }
    #pragma unroll
    for (int m = 1; m < 64; m <<= 1) acc += __shfl_xor(acc, m);
    if ((tid & 63) == 0) red[tid >> 6] = acc;
    __syncthreads();
    if (tid < 64) {
        float v = (tid < 16) ? red[tid] : 0.f;
        #pragma unroll
        for (int m = 1; m < 16; m <<= 1) v += __shfl_xor(v, m);
        if (tid == 0) out[0] = v * (1.0f / (float)NROWS);
    }
}

extern "C" void kernel_launch(void* const* d_in, const int* in_sizes, int n_in,
                              void* d_out, int out_size, void* d_ws, size_t ws_size,
                              hipStream_t stream) {
    const float* zi = (const float*)d_in[0];
    const float* zj = (const float*)d_in[1];
    float* out = (float*)d_out;

    unsigned short* zn = (unsigned short*)d_ws;                    // 2 MB
    float* partial = (float*)((char*)d_ws + NROWS * DDIM * 2);     // 512 KB
    float* posv = partial + NCB * NROWS;                           // 16 KB

    k_normalize<<<NROWS / 4, 256, 0, stream>>>(zi, zj, zn);
    k_simlse<<<NCB * (NCB + 1) / 2, 256, 0, stream>>>(zn, partial, posv);
    k_finalize<<<1, 1024, 0, stream>>>(partial, posv, out);
}

// Round 6
// 77.676 us; speedup vs baseline: 1.6096x; 1.3823x over previous
//
#include <hip/hip_runtime.h>

// NT-Xent (SimCLR) loss, B=2048, D=256, N=4096, T=0.5, eps=1e-8.
// R6: R5's single-block finalize cost ~30us (cross-XCD dirty-line reads,
// one CU of MLP). Revert to 16-block rowlse, fold the last 16-way sum in
// via device-scope atomicAdd on out[0] (zeroed by k_normalize block 0;
// stream order guarantees visibility). 3 launches, all multi-block.
// Fixed harness floor: ~42us d_ws poison fill + d_in restore per iter.

#define NROWS 4096
#define DDIM 256
#define BHALF 2048
#define TILE 128
#define BK 64
#define LDP 72      // padded LDS row stride (shorts): 144B = 9*16B, 2-way banks (free)
#define NCB 32      // 4096/128 tile indices
#define INV_T 2.0f

typedef short bf16x8 __attribute__((ext_vector_type(8)));
typedef float f32x4 __attribute__((ext_vector_type(4)));

__device__ inline unsigned short f2bf(float f) {
    union { float f; unsigned u; } c; c.f = f;
    unsigned u = c.u + 0x7fffu + ((c.u >> 16) & 1u);  // RNE
    return (unsigned short)(u >> 16);
}

// ---- Kernel 1: row-normalize z=[z_i;z_j] into bf16 zn[4096][256] ----------
__global__ __launch_bounds__(256) void k_normalize(
    const float* __restrict__ zi, const float* __restrict__ zj,
    unsigned short* __restrict__ zn, float* __restrict__ out) {
    if (blockIdx.x == 0 && threadIdx.x == 0) out[0] = 0.f;  // for k_rowlse atomics
    const int wave = threadIdx.x >> 6, lane = threadIdx.x & 63;
    const int row = blockIdx.x * 4 + wave;
    const float* src = (row < BHALF) ? (zi + row * DDIM)
                                     : (zj + (row - BHALF) * DDIM);
    const float4 v = ((const float4*)src)[lane];
    float ss = v.x * v.x + v.y * v.y + v.z * v.z + v.w * v.w;
    #pragma unroll
    for (int m = 1; m < 64; m <<= 1) ss += __shfl_xor(ss, m);
    const float scale = 1.0f / fmaxf(sqrtf(ss), 1e-8f);
    ushort4 o;
    o.x = f2bf(v.x * scale); o.y = f2bf(v.y * scale);
    o.z = f2bf(v.z * scale); o.w = f2bf(v.w * scale);
    ((ushort4*)(zn + row * DDIM))[lane] = o;
}

// ---- Kernel 2: upper-triangle LDS-tiled sim GEMM + exp-sum ----------------
// grid = 528 linear blocks -> (bx,by), by>=bx. Block 256 thr = 2x2 waves,
// each wave 64x64 via 4x4 mfma_f32_16x16x32_bf16.
__global__ __launch_bounds__(256) void k_simlse(
    const unsigned short* __restrict__ zn,
    float* __restrict__ partial,     // [NCB][4096], each slot 1 writer
    float* __restrict__ posv) {      // [4096]
    __shared__ unsigned short As[TILE * LDP];
    __shared__ unsigned short Bs[TILE * LDP];
    __shared__ float pscratch[TILE];   // row sums cross-wc
    __shared__ float cscratch[TILE];   // col sums cross-wr

    // triangle decode: block t -> (bx, by), by >= bx
    int t = blockIdx.x, bx = 0, rem = NCB;
    while (t >= rem) { t -= rem; ++bx; --rem; }
    const int by = bx + t;

    const int tid = threadIdx.x;
    const int wave = tid >> 6, lane = tid & 63;
    const int quad = lane >> 4, l15 = lane & 15;
    const int wr = wave >> 1, wc = wave & 1;
    const int rowBase = bx * TILE;
    const int colBase = by * TILE;

    f32x4 acc[4][4] = {};

    #pragma unroll
    for (int kb = 0; kb < DDIM / BK; ++kb) {
        __syncthreads();
        #pragma unroll
        for (int i = 0; i < 4; ++i) {
            const int flat = tid + i * 256;
            const int r = flat >> 3, c = flat & 7;
            *(bf16x8*)&As[r * LDP + c * 8] =
                *(const bf16x8*)&zn[(rowBase + r) * DDIM + kb * BK + c * 8];
            *(bf16x8*)&Bs[r * LDP + c * 8] =
                *(const bf16x8*)&zn[(colBase + r) * DDIM + kb * BK + c * 8];
        }
        __syncthreads();
        #pragma unroll
        for (int s = 0; s < 2; ++s) {
            bf16x8 af[4], bf[4];
            #pragma unroll
            for (int mt = 0; mt < 4; ++mt)
                af[mt] = *(const bf16x8*)&As[(wr * 64 + mt * 16 + l15) * LDP + s * 32 + quad * 8];
            #pragma unroll
            for (int nt = 0; nt < 4; ++nt)
                bf[nt] = *(const bf16x8*)&Bs[(wc * 64 + nt * 16 + l15) * LDP + s * 32 + quad * 8];
            #pragma unroll
            for (int mt = 0; mt < 4; ++mt)
                #pragma unroll
                for (int nt = 0; nt < 4; ++nt)
                    acc[mt][nt] = __builtin_amdgcn_mfma_f32_16x16x32_bf16(
                        af[mt], bf[nt], acc[mt][nt], 0, 0, 0);
        }
    }

    // Epilogue. C/D layout: col = lane&15, row = quad*4 + r.
    float rsum[4][4];          // [mt][r] row-sums (post-butterfly: all lanes)
    float csum[4] = {};        // [nt] per-lane col partial over 16 rows
    #pragma unroll
    for (int mt = 0; mt < 4; ++mt) {
        #pragma unroll
        for (int r = 0; r < 4; ++r) {
            const int grow = rowBase + wr * 64 + mt * 16 + quad * 4 + r;
            float s = 0.f;
            #pragma unroll
            for (int nt = 0; nt < 4; ++nt) {
                const int gcol = colBase + wc * 64 + nt * 16 + l15;
                const float simv = acc[mt][nt][r] * INV_T;
                const float e = (gcol != grow) ? __expf(simv) : 0.f;
                s += e;
                csum[nt] += e;
                if (gcol == grow + BHALF) {       // only in by==bx+16 blocks
                    posv[grow] = simv;            // sim symmetric -> both rows
                    posv[gcol] = simv;
                }
            }
            s += __shfl_xor(s, 1); s += __shfl_xor(s, 2);
            s += __shfl_xor(s, 4); s += __shfl_xor(s, 8);
            rsum[mt][r] = s;
        }
    }
    // col reduce across quads (row-index bits 4,5 of lane)
    #pragma unroll
    for (int nt = 0; nt < 4; ++nt) {
        csum[nt] += __shfl_xor(csum[nt], 16);
        csum[nt] += __shfl_xor(csum[nt], 32);
    }

    __syncthreads();
    if (wc == 0 && l15 == 0) {
        #pragma unroll
        for (int mt = 0; mt < 4; ++mt)
            #pragma unroll
            for (int r = 0; r < 4; ++r)
                pscratch[wr * 64 + mt * 16 + quad * 4 + r] = rsum[mt][r];
    }
    if (wr == 0 && quad == 0) {
        #pragma unroll
        for (int nt = 0; nt < 4; ++nt)
            cscratch[wc * 64 + nt * 16 + l15] = csum[nt];
    }
    __syncthreads();
    if (wc == 1 && l15 == 0) {    // row-sums -> partial[by][rowBase..]
        #pragma unroll
        for (int mt = 0; mt < 4; ++mt)
            #pragma unroll
            for (int r = 0; r < 4; ++r) {
                const int lr = wr * 64 + mt * 16 + quad * 4 + r;
                partial[by * NROWS + rowBase + lr] = rsum[mt][r] + pscratch[lr];
            }
    }
    if (bx != by && wr == 1 && quad == 0) {  // col-sums -> partial[bx][colBase..]
        #pragma unroll
        for (int nt = 0; nt < 4; ++nt) {
            const int lc = wc * 64 + nt * 16 + l15;
            partial[bx * NROWS + colBase + lc] = csum[nt] + cscratch[lc];
        }
    }
}

// ---- Kernel 3: 16-block rowlse + atomic final sum -------------------------
__global__ __launch_bounds__(256) void k_rowlse(
    const float* __restrict__ partial, const float* __restrict__ posv,
    float* __restrict__ out) {
    __shared__ float red[4];
    const int tid = threadIdx.x;
    const int row = blockIdx.x * 256 + tid;
    float s = 0.f;
    #pragma unroll
    for (int p = 0; p < NCB; ++p) s += partial[p * NROWS + row];
    float v = __logf(s) - posv[row];
    #pragma unroll
    for (int m = 1; m < 64; m <<= 1) v += __shfl_xor(v, m);
    if ((tid & 63) == 0) red[tid >> 6] = v;
    __syncthreads();
    if (tid == 0)
        atomicAdd(out, (red[0] + red[1] + red[2] + red[3]) * (1.0f / (float)NROWS));
}

extern "C" void kernel_launch(void* const* d_in, const int* in_sizes, int n_in,
                              void* d_out, int out_size, void* d_ws, size_t ws_size,
                              hipStream_t stream) {
    const float* zi = (const float*)d_in[0];
    const float* zj = (const float*)d_in[1];
    float* out = (float*)d_out;

    unsigned short* zn = (unsigned short*)d_ws;                    // 2 MB
    float* partial = (float*)((char*)d_ws + NROWS * DDIM * 2);     // 512 KB
    float* posv = partial + NCB * NROWS;                           // 16 KB

    k_normalize<<<NROWS / 4, 256, 0, stream>>>(zi, zj, zn, out);
    k_simlse<<<NCB * (NCB + 1) / 2, 256, 0, stream>>>(zn, partial, posv);
    k_rowlse<<<16, 256, 0, stream>>>(partial, posv, out);
}